// Round 4
// baseline (4102.980 us; speedup 1.0000x reference)
//
#include <hip/hip_runtime.h>

#define NT 4096
#define DIN 2048
#define NF 16384
#define KTOP 32
#define KAUX 256
#define DEAD_TH 100

static constexpr size_t RECON_ELEMS = (size_t)NT * DIN;   // 8388608
static constexpr size_t COEFF_ELEMS = (size_t)NT * NF;    // 67108864

// monotonic float->uint key: larger float => larger key
__device__ __forceinline__ unsigned f2k(float f) {
  unsigned b = __float_as_uint(f);
  return (b & 0x80000000u) ? ~b : (b | 0x80000000u);
}
__device__ __forceinline__ float k2f(unsigned k) {
  unsigned b = (k & 0x80000000u) ? (k & 0x7fffffffu) : ~k;
  return __uint_as_float(b);
}

// ---------------------------------------------------------------- init
__global__ void k_init(double* sums, int* active) {
  int tid = blockIdx.x * 256 + threadIdx.x;
  if (tid < 2) sums[tid] = 0.0;
  for (int f = tid; f < NF; f += 64 * 256) active[f] = 0;
}

// ---------------------------------------------------------------- MFMA GEMM (f16 split-3)
// C[4096,16384] = A[4096,2048] @ B[2048,16384] + bias  in ~fp32 precision via
// a = a_hi + a_lo (f16 RTZ split, scaled x16), b = b_hi + b_lo (scaled x512):
// a*b ~= ah*bh + ah*bl + al*bh  (dropped al*bl ~ 2^-20 rel), fp32 MFMA accum.
// BK=32 / 32KB LDS -> 4 blocks/CU for cross-block phase overlap (MFMA||VALU).
typedef _Float16 h8 __attribute__((ext_vector_type(8)));
typedef float f4 __attribute__((ext_vector_type(4)));

// split t into f16 hi + f16 lo (residual), packed as 2x16-bit in one dword each
__device__ __forceinline__ void split2(float t0, float t1, unsigned& hi, unsigned& lo) {
  auto h = __builtin_amdgcn_cvt_pkrtz(t0, t1);       // __fp16 ext_vector(2)
  union UH { decltype(h) v; unsigned u; };
  UH uh; uh.v = h; hi = uh.u;
  float r0 = t0 - (float)h.x, r1 = t1 - (float)h.y;
  auto l = __builtin_amdgcn_cvt_pkrtz(r0, r1);
  UH ul; ul.v = l; lo = ul.u;
}

#define BM 128
#define BN 128
#define BK 32

__global__ __launch_bounds__(256, 4) void k_gemm_mfma(const float* __restrict__ A,
                                                      const float* __restrict__ B,
                                                      const float* __restrict__ bias,
                                                      float* __restrict__ C) {
  // f16 tiles, K-contiguous rows (64 bytes = 32 f16 per row)
  // swizzle: 16B-chunk index ^= (row>>1)&3  -> 2-way bank aliasing on frag reads (free)
  __shared__ __align__(16) char As_hi[BM * 64];   // 8 KB each
  __shared__ __align__(16) char As_lo[BM * 64];
  __shared__ __align__(16) char Bs_hi[BN * 64];
  __shared__ __align__(16) char Bs_lo[BN * 64];

  const int tid = threadIdx.x;
  const int lane = tid & 63;
  const int w = tid >> 6;
  const int wm = (w >> 1) * 64, wn = (w & 1) * 64;
  const int row0 = blockIdx.y * BM, col0 = blockIdx.x * BN;

  const float* Ag = A + (size_t)row0 * DIN;
  const float* Bg = B + col0;

  float4 areg[4];     // A tile: 4 float4 per thread
  float breg[2][8];   // B tile: 2 (col, k-chunk) x 8 k-values per thread (transposing load)

  f4 acc[4][4];
  #pragma unroll
  for (int i = 0; i < 4; i++)
    #pragma unroll
    for (int j = 0; j < 4; j++) acc[i][j] = (f4){0.f, 0.f, 0.f, 0.f};

  auto loadA = [&](int k0) {
    #pragma unroll
    for (int it = 0; it < 4; it++) {
      int q = it * 256 + tid;
      int m = q >> 3, c4 = q & 7;                       // row m, float4 index c4 (k = c4*4)
      areg[it] = *(const float4*)(Ag + (size_t)m * DIN + k0 + c4 * 4);
    }
  };
  auto loadB = [&](int k0) {
    #pragma unroll
    for (int it = 0; it < 2; it++) {
      int p = it * 256 + tid;
      int n = p & 127, kc = p >> 7;                     // col n, k-chunk kc (8 k's), kc 0..3 over 2 its
      const float* bp = Bg + (size_t)(k0 + kc * 8) * NF + n;
      #pragma unroll
      for (int i = 0; i < 8; i++) breg[it][i] = bp[(size_t)i * NF];  // per-instr: 64 lanes = 256B contiguous
    }
  };

  auto convert_write = [&]() {
    #pragma unroll
    for (int it = 0; it < 4; it++) {
      int q = it * 256 + tid;
      int m = q >> 3, c4 = q & 7;
      float4 v = areg[it];
      unsigned h01, l01, h23, l23;
      split2(v.x * 16.f, v.y * 16.f, h01, l01);
      split2(v.z * 16.f, v.w * 16.f, h23, l23);
      unsigned chunk = ((unsigned)c4 >> 1) ^ (((unsigned)m >> 1) & 3u);
      unsigned off = (unsigned)m * 64u + (chunk << 4) + ((unsigned)c4 & 1u) * 8u;
      *(uint2*)(As_hi + off) = make_uint2(h01, h23);
      *(uint2*)(As_lo + off) = make_uint2(l01, l23);
    }
    #pragma unroll
    for (int it = 0; it < 2; it++) {
      int p = it * 256 + tid;
      int n = p & 127, kc = p >> 7;
      unsigned hh[4], ll[4];
      #pragma unroll
      for (int j = 0; j < 4; j++)
        split2(breg[it][2 * j] * 512.f, breg[it][2 * j + 1] * 512.f, hh[j], ll[j]);
      unsigned chunk = (unsigned)kc ^ (((unsigned)n >> 1) & 3u);
      unsigned off = (unsigned)n * 64u + (chunk << 4);
      *(uint4*)(Bs_hi + off) = make_uint4(hh[0], hh[1], hh[2], hh[3]);
      *(uint4*)(Bs_lo + off) = make_uint4(ll[0], ll[1], ll[2], ll[3]);
    }
  };

  auto compute = [&]() {
    const unsigned kchunk = (unsigned)(lane >> 4);     // 0..3, 8 f16 each
    h8 ah[4], al[4], bh[4], bl[4];
    #pragma unroll
    for (int mt = 0; mt < 4; mt++) {
      unsigned r = (unsigned)(wm + mt * 16 + (lane & 15));
      unsigned off = r * 64u + ((kchunk ^ ((r >> 1) & 3u)) << 4);
      ah[mt] = *(const h8*)(As_hi + off);
      al[mt] = *(const h8*)(As_lo + off);
    }
    #pragma unroll
    for (int nt = 0; nt < 4; nt++) {
      unsigned r = (unsigned)(wn + nt * 16 + (lane & 15));
      unsigned off = r * 64u + ((kchunk ^ ((r >> 1) & 3u)) << 4);
      bh[nt] = *(const h8*)(Bs_hi + off);
      bl[nt] = *(const h8*)(Bs_lo + off);
    }
    #pragma unroll
    for (int mt = 0; mt < 4; mt++)
      #pragma unroll
      for (int nt = 0; nt < 4; nt++) {
        acc[mt][nt] = __builtin_amdgcn_mfma_f32_16x16x32_f16(ah[mt], bh[nt], acc[mt][nt], 0, 0, 0);
        acc[mt][nt] = __builtin_amdgcn_mfma_f32_16x16x32_f16(ah[mt], bl[nt], acc[mt][nt], 0, 0, 0);
        acc[mt][nt] = __builtin_amdgcn_mfma_f32_16x16x32_f16(al[mt], bh[nt], acc[mt][nt], 0, 0, 0);
      }
  };

  loadA(0); loadB(0);
  for (int kt = 0; kt < DIN / BK; kt++) {
    convert_write();                 // regs (tile kt) -> LDS
    __syncthreads();                 // LDS ready for all waves
    if (kt + 1 < DIN / BK) { loadA((kt + 1) * BK); loadB((kt + 1) * BK); }  // prefetch under compute
    compute();
    __syncthreads();                 // all waves done reading before overwrite
  }

  // epilogue: C/D layout col=lane&15, row=(lane>>4)*4+reg  [m89-verified]
  const float inv = 1.0f / 8192.0f;  // undo 16*512 scaling
  #pragma unroll
  for (int nt = 0; nt < 4; nt++) {
    int col = col0 + wn + nt * 16 + (lane & 15);
    float bv = bias[col];
    #pragma unroll
    for (int mt = 0; mt < 4; mt++) {
      int rowb = row0 + wm + mt * 16 + ((lane >> 4) << 2);
      #pragma unroll
      for (int r = 0; r < 4; r++)
        C[(size_t)(rowb + r) * NF + col] = acc[mt][nt][r] * inv + bv;
    }
  }
}

// ---------------------------------------------------------------- per-row top-32
// Exact radix-select (4x8-bit passes), ties -> lowest index (matches lax.top_k).
// Row (64 KB) staged into LDS once with coalesced loads; all passes read LDS.
// Global traffic = 1 read + 1 write of the row (structural minimum).
__global__ __launch_bounds__(512, 2) void k_topk(float* __restrict__ pre,
                                                 int* __restrict__ topk_idx,
                                                 float* __restrict__ topk_val,
                                                 int* __restrict__ active) {
  __shared__ __align__(16) float srow[NF];     // 64 KB
  __shared__ unsigned hist[8][256];            // 8 KB, per-wave copies
  __shared__ unsigned redbuf[8];
  __shared__ int sel_idx[KTOP];
  __shared__ float sel_val[KTOP];
  __shared__ unsigned s_prefix;
  __shared__ int s_remaining, s_scnt, s_last;

  const int tid = threadIdx.x;
  const int wv = tid >> 6;                     // 0..7
  const int row = blockIdx.x;
  float* rowp = pre + (size_t)row * NF;

  // stage row into LDS, fully coalesced (lane-stride 16B)
  {
    const float4* g4 = (const float4*)rowp;
    float4* s4 = (float4*)srow;
    #pragma unroll
    for (int i = 0; i < 8; i++) s4[i * 512 + tid] = g4[i * 512 + tid];
  }
  if (tid == 0) { s_prefix = 0u; s_remaining = KTOP; s_scnt = 0; }
  __syncthreads();

  const float4* s4 = (const float4*)srow;

  for (int pass = 0; pass < 4; pass++) {
    const int shift = 24 - pass * 8;
    const unsigned mask_hi = pass ? (0xFFFFFFFFu << (shift + 8)) : 0u;
    {
      unsigned* hp = &hist[0][0];
      #pragma unroll
      for (int q = 0; q < 4; q++) hp[q * 512 + tid] = 0;
    }
    __syncthreads();
    const unsigned pfx = s_prefix;
    #pragma unroll
    for (int i = 0; i < 8; i++) {
      float4 v = s4[i * 512 + tid];
      unsigned k0 = f2k(v.x), k1 = f2k(v.y), k2 = f2k(v.z), k3 = f2k(v.w);
      if ((k0 & mask_hi) == pfx) atomicAdd(&hist[wv][(k0 >> shift) & 255u], 1u);
      if ((k1 & mask_hi) == pfx) atomicAdd(&hist[wv][(k1 >> shift) & 255u], 1u);
      if ((k2 & mask_hi) == pfx) atomicAdd(&hist[wv][(k2 >> shift) & 255u], 1u);
      if ((k3 & mask_hi) == pfx) atomicAdd(&hist[wv][(k3 >> shift) & 255u], 1u);
    }
    __syncthreads();
    if (tid < 256) {
      unsigned h = 0;
      #pragma unroll
      for (int w8 = 0; w8 < 8; w8++) h += hist[w8][tid];
      hist[0][tid] = h;
    }
    __syncthreads();
    if (tid == 0) {
      int rem = s_remaining; unsigned above = 0;
      for (int b = 255; b >= 0; b--) {
        unsigned hh = hist[0][b];
        if (above + hh >= (unsigned)rem) {
          s_prefix |= ((unsigned)b) << shift;
          s_remaining = rem - (int)above;
          break;
        }
        above += hh;
      }
    }
    __syncthreads();
  }
  const unsigned T = s_prefix;   // key of the 32nd largest
  const int r = s_remaining;     // how many ==T to take (lowest indices first)

  // gather strictly-greater (set semantics; order within sel irrelevant)
  #pragma unroll
  for (int i = 0; i < 8; i++) {
    float4 v = s4[i * 512 + tid];
    const int bidx = (i * 512 + tid) * 4;
    float vv[4] = {v.x, v.y, v.z, v.w};
    #pragma unroll
    for (int e = 0; e < 4; e++) {
      unsigned k = f2k(vv[e]);
      if (k > T) {
        int p = atomicAdd(&s_scnt, 1);
        sel_idx[p] = bidx + e;
        sel_val[p] = vv[e];
      }
    }
  }
  __syncthreads();
  // r smallest indices among key==T: iterative block-wide min-index reduction
  const int cg = s_scnt;         // == KTOP - r
  int last = -1;
  const float tv = k2f(T);
  for (int a = 0; a < r; a++) {
    unsigned mymin = 0xFFFFFFFFu;
    #pragma unroll
    for (int i = 0; i < 8; i++) {
      float4 v = s4[i * 512 + tid];
      const int bidx = (i * 512 + tid) * 4;
      float vv[4] = {v.x, v.y, v.z, v.w};
      #pragma unroll
      for (int e = 0; e < 4; e++) {
        int idx = bidx + e;
        if (f2k(vv[e]) == T && idx > last && (unsigned)idx < mymin) mymin = (unsigned)idx;
      }
    }
    #pragma unroll
    for (int o = 32; o > 0; o >>= 1) {
      unsigned ot = __shfl_down(mymin, o);
      mymin = ot < mymin ? ot : mymin;
    }
    if ((tid & 63) == 0) redbuf[wv] = mymin;
    __syncthreads();
    if (tid == 0) {
      unsigned m = redbuf[0];
      #pragma unroll
      for (int w8 = 1; w8 < 8; w8++) m = redbuf[w8] < m ? redbuf[w8] : m;
      sel_idx[cg + a] = (int)m;
      sel_val[cg + a] = tv;
      s_last = (int)m;
    }
    __syncthreads();
    last = s_last;
  }

  // zero the row (coalesced), then scatter relu(top-k)
  float4 z = {0.f, 0.f, 0.f, 0.f};
  float4* wp4 = (float4*)rowp;
  #pragma unroll
  for (int i = 0; i < 8; i++) wp4[i * 512 + tid] = z;
  __syncthreads();
  if (tid < KTOP) {
    int idx = sel_idx[tid];
    float v = sel_val[tid];
    float c = v > 0.f ? v : 0.f;
    rowp[idx] = c;
    topk_idx[row * KTOP + tid] = idx;
    topk_val[row * KTOP + tid] = c;
    if (v > 0.f) active[idx] = 1;
  }
}

// ---------------------------------------------------------------- dead scan (sorted)
__global__ void k_dead(const int* __restrict__ steps, const int* __restrict__ active,
                       int* __restrict__ dead_idx, int* __restrict__ dead_cnt) {
  __shared__ int cnt[256];
  const int tid = threadIdx.x;
  int c = 0;
  for (int f = tid * 64; f < tid * 64 + 64; f++) {
    int ns = active[f] ? 0 : steps[f] + 1;
    if (ns >= DEAD_TH) c++;
  }
  cnt[tid] = c;
  __syncthreads();
  if (tid == 0) {
    int run = 0;
    for (int t = 0; t < 256; t++) { int x = cnt[t]; cnt[t] = run; run += x; }
    *dead_cnt = run;
  }
  __syncthreads();
  int off = cnt[tid];
  for (int f = tid * 64; f < tid * 64 + 64; f++) {
    int ns = active[f] ? 0 : steps[f] + 1;
    if (ns >= DEAD_TH) dead_idx[off++] = f;
  }
}

// ---------------------------------------------------------------- gather dead W_enc columns
__global__ void k_gather(const float* __restrict__ Wenc, const int* __restrict__ dead_idx,
                         const int* __restrict__ dead_cnt, float* __restrict__ w_dead, int Dcap) {
  int D = *dead_cnt; if (D > Dcap) D = Dcap;
  const size_t total = (size_t)D * DIN;
  for (size_t u = (size_t)blockIdx.x * 256 + threadIdx.x; u < total; u += (size_t)gridDim.x * 256) {
    const size_t j = u >> 11, i = u & 2047;
    w_dead[u] = Wenc[i * NF + dead_idx[j]];
  }
}

// ---------------------------------------------------------------- sparse decode + MSE
__global__ __launch_bounds__(256) void k_recon(const float* __restrict__ x, const float* __restrict__ Wdec,
                                               const float* __restrict__ bdec,
                                               const int* __restrict__ topk_idx,
                                               const float* __restrict__ topk_val,
                                               float* __restrict__ recon, double* __restrict__ sums) {
  __shared__ int fidx[KTOP];
  __shared__ float fval[KTOP];
  __shared__ float wred[4];
  const int tid = threadIdx.x, lane = tid & 63, wv = tid >> 6;
  const int row = blockIdx.x;
  if (tid < KTOP) { fidx[tid] = topk_idx[row * KTOP + tid]; fval[tid] = topk_val[row * KTOP + tid]; }
  __syncthreads();
  float4 a0 = {0,0,0,0}, a1 = {0,0,0,0};
  for (int j = 0; j < KTOP; j++) {
    const float c = fval[j];
    if (c > 0.f) {
      const float4* w = (const float4*)(Wdec + (size_t)fidx[j] * DIN);
      float4 w0 = w[tid], w1 = w[256 + tid];
      a0.x = fmaf(c, w0.x, a0.x); a0.y = fmaf(c, w0.y, a0.y);
      a0.z = fmaf(c, w0.z, a0.z); a0.w = fmaf(c, w0.w, a0.w);
      a1.x = fmaf(c, w1.x, a1.x); a1.y = fmaf(c, w1.y, a1.y);
      a1.z = fmaf(c, w1.z, a1.z); a1.w = fmaf(c, w1.w, a1.w);
    }
  }
  const float4* b4 = (const float4*)bdec;
  float4 b0 = b4[tid], b1 = b4[256 + tid];
  float4 r0 = {a0.x + b0.x, a0.y + b0.y, a0.z + b0.z, a0.w + b0.w};
  float4 r1 = {a1.x + b1.x, a1.y + b1.y, a1.z + b1.z, a1.w + b1.w};
  float4* rout = (float4*)(recon + (size_t)row * DIN);
  rout[tid] = r0; rout[256 + tid] = r1;
  const float4* x4 = (const float4*)(x + (size_t)row * DIN);
  float4 x0 = x4[tid], x1 = x4[256 + tid];
  float s = 0.f, d;
  d = r0.x - x0.x; s = fmaf(d, d, s);
  d = r0.y - x0.y; s = fmaf(d, d, s);
  d = r0.z - x0.z; s = fmaf(d, d, s);
  d = r0.w - x0.w; s = fmaf(d, d, s);
  d = r1.x - x1.x; s = fmaf(d, d, s);
  d = r1.y - x1.y; s = fmaf(d, d, s);
  d = r1.z - x1.z; s = fmaf(d, d, s);
  d = r1.w - x1.w; s = fmaf(d, d, s);
  #pragma unroll
  for (int o = 32; o > 0; o >>= 1) s += __shfl_down(s, o);
  if (lane == 0) wred[wv] = s;
  __syncthreads();
  if (tid == 0) {
    double t = (double)wred[0] + (double)wred[1] + (double)wred[2] + (double)wred[3];
    atomicAdd(&sums[0], t);
  }
}

// ---------------------------------------------------------------- aux loss
__global__ __launch_bounds__(256) void k_aux(const float* __restrict__ x, const float* __restrict__ Wenc,
                                             const float* __restrict__ benc, const float* __restrict__ Wdec,
                                             const float* __restrict__ bdec, const float* __restrict__ recon,
                                             const int* __restrict__ dead_idx, const int* __restrict__ dead_cnt,
                                             const float* __restrict__ w_dead, int Dcap,
                                             double* __restrict__ sums) {
  __shared__ float xrow[DIN];
  __shared__ unsigned hist[4][256];
  __shared__ int eqj[2048];
  __shared__ int self_[KAUX];
  __shared__ float selc[KAUX];
  __shared__ float wred[4];
  __shared__ unsigned s_prefix;
  __shared__ int s_remaining, s_scnt, s_eqcnt;

  const int tid = threadIdx.x, lane = tid & 63, wv = tid >> 6;
  const int row = blockIdx.x;
  const float4* xg4 = (const float4*)(x + (size_t)row * DIN);
  float4* xr4 = (float4*)xrow;
  xr4[tid] = xg4[tid];
  xr4[256 + tid] = xg4[256 + tid];
  if (tid == 0) { s_prefix = 0u; s_remaining = KAUX; s_scnt = 0; s_eqcnt = 0; }
  __syncthreads();
  const int D = *dead_cnt;

  auto pdval = [&](int jj) -> float {  // whole wave computes pre of dead feature jj
    const int f = dead_idx[jj];
    float p = 0.f;
    if (jj < Dcap) {
      const float* wd = w_dead + (size_t)jj * DIN;
      for (int i = lane; i < DIN; i += 64) p = fmaf(xrow[i], wd[i], p);
    } else {
      const float* wc = Wenc + f;
      for (int i = lane; i < DIN; i += 64) p = fmaf(xrow[i], wc[(size_t)i * NF], p);
    }
    #pragma unroll
    for (int o = 32; o > 0; o >>= 1) p += __shfl_down(p, o);
    p = __shfl(p, 0);
    return p + benc[f];
  };

  if (D <= KAUX) {
    for (int jj = wv; jj < D; jj += 4) {
      float v = pdval(jj);
      if (lane == 0) { self_[jj] = dead_idx[jj]; selc[jj] = v > 0.f ? v : 0.f; }
    }
    if (tid == 0) s_scnt = D;
    __syncthreads();
  } else {
    for (int pass = 0; pass < 4; pass++) {
      const int shift = 24 - pass * 8;
      const unsigned mask_hi = pass ? (0xFFFFFFFFu << (shift + 8)) : 0u;
      hist[0][tid] = 0; hist[1][tid] = 0; hist[2][tid] = 0; hist[3][tid] = 0;
      __syncthreads();
      const unsigned pfx = s_prefix;
      for (int jj = wv; jj < D; jj += 4) {
        float v = pdval(jj);
        if (lane == 0) {
          unsigned k = f2k(v);
          if ((k & mask_hi) == pfx) atomicAdd(&hist[wv][(k >> shift) & 255u], 1u);
        }
      }
      __syncthreads();
      unsigned h = hist[0][tid] + hist[1][tid] + hist[2][tid] + hist[3][tid];
      hist[0][tid] = h;
      __syncthreads();
      if (tid == 0) {
        int rem = s_remaining; unsigned above = 0;
        for (int b = 255; b >= 0; b--) {
          unsigned hh = hist[0][b];
          if (above + hh >= (unsigned)rem) {
            s_prefix |= ((unsigned)b) << shift;
            s_remaining = rem - (int)above;
            break;
          }
          above += hh;
        }
      }
      __syncthreads();
    }
    const unsigned T = s_prefix;
    const int r = s_remaining;
    for (int jj = wv; jj < D; jj += 4) {
      float v = pdval(jj);
      if (lane == 0) {
        unsigned k = f2k(v);
        if (k > T) { int p = atomicAdd(&s_scnt, 1); self_[p] = dead_idx[jj]; selc[p] = v > 0.f ? v : 0.f; }
        else if (k == T) { int p = atomicAdd(&s_eqcnt, 1); if (p < 2048) eqj[p] = jj; }
      }
    }
    __syncthreads();
    if (tid == 0) {
      int cnt = s_eqcnt < 2048 ? s_eqcnt : 2048;
      const int base = s_scnt;  // == KAUX - r
      const float tv = k2f(T);
      const float tc = tv > 0.f ? tv : 0.f;
      for (int a = 0; a < r; a++) {
        int bestpos = -1, bestj = 0x7fffffff;
        for (int q = 0; q < cnt; q++) { int j = eqj[q]; if (j >= 0 && j < bestj) { bestj = j; bestpos = q; } }
        if (bestpos < 0) break;
        eqj[bestpos] = -1;
        self_[base + a] = dead_idx[bestj];
        selc[base + a] = tc;
      }
      s_scnt = base + r;
    }
    __syncthreads();
  }

  const int scnt = s_scnt;
  float4 a0 = {0,0,0,0}, a1 = {0,0,0,0};
  for (int s = 0; s < scnt; s++) {
    const float c = selc[s];
    if (c > 0.f) {
      const float4* w = (const float4*)(Wdec + (size_t)self_[s] * DIN);
      float4 w0 = w[tid], w1 = w[256 + tid];
      a0.x = fmaf(c, w0.x, a0.x); a0.y = fmaf(c, w0.y, a0.y);
      a0.z = fmaf(c, w0.z, a0.z); a0.w = fmaf(c, w0.w, a0.w);
      a1.x = fmaf(c, w1.x, a1.x); a1.y = fmaf(c, w1.y, a1.y);
      a1.z = fmaf(c, w1.z, a1.z); a1.w = fmaf(c, w1.w, a1.w);
    }
  }
  const float4* b4 = (const float4*)bdec;
  float4 b0 = b4[tid], b1 = b4[256 + tid];
  const float4* rc4 = (const float4*)(recon + (size_t)row * DIN);
  float4 r0 = rc4[tid], r1 = rc4[256 + tid];
  float4 x0 = xr4[tid], x1 = xr4[256 + tid];
  float s = 0.f, d;
  d = (a0.x + b0.x) - (x0.x - r0.x); s = fmaf(d, d, s);
  d = (a0.y + b0.y) - (x0.y - r0.y); s = fmaf(d, d, s);
  d = (a0.z + b0.z) - (x0.z - r0.z); s = fmaf(d, d, s);
  d = (a0.w + b0.w) - (x0.w - r0.w); s = fmaf(d, d, s);
  d = (a1.x + b1.x) - (x1.x - r1.x); s = fmaf(d, d, s);
  d = (a1.y + b1.y) - (x1.y - r1.y); s = fmaf(d, d, s);
  d = (a1.z + b1.z) - (x1.z - r1.z); s = fmaf(d, d, s);
  d = (a1.w + b1.w) - (x1.w - r1.w); s = fmaf(d, d, s);
  #pragma unroll
  for (int o = 32; o > 0; o >>= 1) s += __shfl_down(s, o);
  if (lane == 0) wred[wv] = s;
  __syncthreads();
  if (tid == 0) {
    double t = (double)wred[0] + (double)wred[1] + (double)wred[2] + (double)wred[3];
    atomicAdd(&sums[1], t);
  }
}

// ---------------------------------------------------------------- scalars
__global__ void k_final(const double* __restrict__ sums, float* __restrict__ out_scalars) {
  const double denom = (double)NT * (double)DIN;
  const double mse = sums[0] / denom;
  const double aux = sums[1] / denom;
  out_scalars[0] = (float)(mse + aux);  // loss
  out_scalars[1] = (float)mse;
  out_scalars[2] = (float)aux;
}

// ---------------------------------------------------------------- launch
extern "C" void kernel_launch(void* const* d_in, const int* in_sizes, int n_in,
                              void* d_out, int out_size, void* d_ws, size_t ws_size,
                              hipStream_t stream) {
  const float* x    = (const float*)d_in[0];
  const float* Wenc = (const float*)d_in[1];
  const float* benc = (const float*)d_in[2];
  const float* Wdec = (const float*)d_in[3];
  const float* bdec = (const float*)d_in[4];
  const int*   steps = (const int*)d_in[5];

  float* out = (float*)d_out;
  float* recon   = out;
  float* coeffs  = out + RECON_ELEMS;
  float* scalars = out + RECON_ELEMS + COEFF_ELEMS;

  char* ws = (char*)d_ws;
  size_t off = 0;
  double* sums   = (double*)(ws + off); off += 64;
  int* active    = (int*)(ws + off);    off += (size_t)NF * 4;
  int* dead_cnt  = (int*)(ws + off);    off += 64;
  int* dead_idx  = (int*)(ws + off);    off += (size_t)NF * 4;
  int* topk_idx  = (int*)(ws + off);    off += (size_t)NT * KTOP * 4;
  float* topk_val= (float*)(ws + off);  off += (size_t)NT * KTOP * 4;
  float* w_dead  = (float*)(ws + off);
  int Dcap = 0;
  if (ws_size > off) {
    size_t cap = (ws_size - off) / ((size_t)DIN * 4);
    Dcap = cap > 1024 ? 1024 : (int)cap;
  }

  k_init<<<64, 256, 0, stream>>>(sums, active);
  dim3 gemm_grid(NF / BN, NT / BM);
  k_gemm_mfma<<<gemm_grid, 256, 0, stream>>>(x, Wenc, benc, coeffs);   // pre -> coeffs region
  k_topk<<<NT, 512, 0, stream>>>(coeffs, topk_idx, topk_val, active);  // pre -> sparse coeffs
  k_dead<<<1, 256, 0, stream>>>(steps, active, dead_idx, dead_cnt);
  k_gather<<<256, 256, 0, stream>>>(Wenc, dead_idx, dead_cnt, w_dead, Dcap);
  k_recon<<<NT, 256, 0, stream>>>(x, Wdec, bdec, topk_idx, topk_val, recon, sums);
  k_aux<<<NT, 256, 0, stream>>>(x, Wenc, benc, Wdec, bdec, recon, dead_idx, dead_cnt, w_dead, Dcap, sums);
  k_final<<<1, 1, 0, stream>>>(sums, scalars);
}

// Round 5
// 1945.270 us; speedup vs baseline: 2.1092x; 2.1092x over previous
//
#include <hip/hip_runtime.h>

#define NT 4096
#define DIN 2048
#define NF 16384
#define KTOP 32
#define KAUX 256
#define DEAD_TH 100

static constexpr size_t RECON_ELEMS = (size_t)NT * DIN;   // 8388608
static constexpr size_t COEFF_ELEMS = (size_t)NT * NF;    // 67108864

// monotonic float->uint key: larger float => larger key
__device__ __forceinline__ unsigned f2k(float f) {
  unsigned b = __float_as_uint(f);
  return (b & 0x80000000u) ? ~b : (b | 0x80000000u);
}
__device__ __forceinline__ float k2f(unsigned k) {
  unsigned b = (k & 0x80000000u) ? (k & 0x7fffffffu) : ~k;
  return __uint_as_float(b);
}

// ---------------------------------------------------------------- init
__global__ void k_init(double* sums, int* active) {
  int tid = blockIdx.x * 256 + threadIdx.x;
  if (tid < 2) sums[tid] = 0.0;
  for (int f = tid; f < NF; f += 64 * 256) active[f] = 0;
}

// ---------------------------------------------------------------- MFMA GEMM (f16 split-3)
// C[4096,16384] = A[4096,2048] @ B[2048,16384] + bias  in ~fp32 precision via
// a = a_hi + a_lo (f16 RTZ split, scaled x16), b = b_hi + b_lo (scaled x512):
// a*b ~= ah*bh + ah*bl + al*bh  (dropped al*bl ~ 2^-20 rel), fp32 MFMA accum.
// BK=32 / 32KB LDS -> 4-5 blocks/CU for cross-block phase overlap (MFMA||VALU).
// launch_bounds(256,2): do NOT force 4 waves/EU — that caps VGPR at 64 and
// spills the 64-VGPR accumulator to scratch (round-4 post-mortem: 6 GB writes).
typedef _Float16 h8 __attribute__((ext_vector_type(8)));
typedef float f4 __attribute__((ext_vector_type(4)));

// split t into f16 hi + f16 lo (residual), packed as 2x16-bit in one dword each
__device__ __forceinline__ void split2(float t0, float t1, unsigned& hi, unsigned& lo) {
  auto h = __builtin_amdgcn_cvt_pkrtz(t0, t1);       // __fp16 ext_vector(2)
  union UH { decltype(h) v; unsigned u; };
  UH uh; uh.v = h; hi = uh.u;
  float r0 = t0 - (float)h.x, r1 = t1 - (float)h.y;
  auto l = __builtin_amdgcn_cvt_pkrtz(r0, r1);
  UH ul; ul.v = l; lo = ul.u;
}

#define BM 128
#define BN 128
#define BK 32

__global__ __launch_bounds__(256, 2) void k_gemm_mfma(const float* __restrict__ A,
                                                      const float* __restrict__ B,
                                                      const float* __restrict__ bias,
                                                      float* __restrict__ C) {
  // f16 tiles, K-contiguous rows (64 bytes = 32 f16 per row)
  // swizzle: 16B-chunk index ^= (row>>1)&3  -> 2-way bank aliasing on frag reads (free)
  __shared__ __align__(16) char As_hi[BM * 64];   // 8 KB each
  __shared__ __align__(16) char As_lo[BM * 64];
  __shared__ __align__(16) char Bs_hi[BN * 64];
  __shared__ __align__(16) char Bs_lo[BN * 64];

  const int tid = threadIdx.x;
  const int lane = tid & 63;
  const int w = tid >> 6;
  const int wm = (w >> 1) * 64, wn = (w & 1) * 64;
  const int row0 = blockIdx.y * BM, col0 = blockIdx.x * BN;

  const float* Ag = A + (size_t)row0 * DIN;
  const float* Bg = B + col0;

  float4 areg[4];     // A tile: 4 float4 per thread
  float breg[2][8];   // B tile: 2 (col, k-chunk) x 8 k-values per thread (transposing load)

  f4 acc[4][4];
  #pragma unroll
  for (int i = 0; i < 4; i++)
    #pragma unroll
    for (int j = 0; j < 4; j++) acc[i][j] = (f4){0.f, 0.f, 0.f, 0.f};

  auto loadA = [&](int k0) {
    #pragma unroll
    for (int it = 0; it < 4; it++) {
      int q = it * 256 + tid;
      int m = q >> 3, c4 = q & 7;                       // row m, float4 index c4 (k = c4*4)
      areg[it] = *(const float4*)(Ag + (size_t)m * DIN + k0 + c4 * 4);
    }
  };
  auto loadB = [&](int k0) {
    #pragma unroll
    for (int it = 0; it < 2; it++) {
      int p = it * 256 + tid;
      int n = p & 127, kc = p >> 7;                     // col n, k-chunk kc (8 k's), kc 0..3 over 2 its
      const float* bp = Bg + (size_t)(k0 + kc * 8) * NF + n;
      #pragma unroll
      for (int i = 0; i < 8; i++) breg[it][i] = bp[(size_t)i * NF];  // per-instr: 64 lanes = 256B contiguous
    }
  };

  auto convert_write = [&]() {
    #pragma unroll
    for (int it = 0; it < 4; it++) {
      int q = it * 256 + tid;
      int m = q >> 3, c4 = q & 7;
      float4 v = areg[it];
      unsigned h01, l01, h23, l23;
      split2(v.x * 16.f, v.y * 16.f, h01, l01);
      split2(v.z * 16.f, v.w * 16.f, h23, l23);
      unsigned chunk = ((unsigned)c4 >> 1) ^ (((unsigned)m >> 1) & 3u);
      unsigned off = (unsigned)m * 64u + (chunk << 4) + ((unsigned)c4 & 1u) * 8u;
      *(uint2*)(As_hi + off) = make_uint2(h01, h23);
      *(uint2*)(As_lo + off) = make_uint2(l01, l23);
    }
    #pragma unroll
    for (int it = 0; it < 2; it++) {
      int p = it * 256 + tid;
      int n = p & 127, kc = p >> 7;
      unsigned hh[4], ll[4];
      #pragma unroll
      for (int j = 0; j < 4; j++)
        split2(breg[it][2 * j] * 512.f, breg[it][2 * j + 1] * 512.f, hh[j], ll[j]);
      unsigned chunk = (unsigned)kc ^ (((unsigned)n >> 1) & 3u);
      unsigned off = (unsigned)n * 64u + (chunk << 4);
      *(uint4*)(Bs_hi + off) = make_uint4(hh[0], hh[1], hh[2], hh[3]);
      *(uint4*)(Bs_lo + off) = make_uint4(ll[0], ll[1], ll[2], ll[3]);
    }
  };

  auto compute = [&]() {
    const unsigned kchunk = (unsigned)(lane >> 4);     // 0..3, 8 f16 each
    h8 ah[4], al[4], bh[4], bl[4];
    #pragma unroll
    for (int mt = 0; mt < 4; mt++) {
      unsigned r = (unsigned)(wm + mt * 16 + (lane & 15));
      unsigned off = r * 64u + ((kchunk ^ ((r >> 1) & 3u)) << 4);
      ah[mt] = *(const h8*)(As_hi + off);
      al[mt] = *(const h8*)(As_lo + off);
    }
    #pragma unroll
    for (int nt = 0; nt < 4; nt++) {
      unsigned r = (unsigned)(wn + nt * 16 + (lane & 15));
      unsigned off = r * 64u + ((kchunk ^ ((r >> 1) & 3u)) << 4);
      bh[nt] = *(const h8*)(Bs_hi + off);
      bl[nt] = *(const h8*)(Bs_lo + off);
    }
    #pragma unroll
    for (int mt = 0; mt < 4; mt++)
      #pragma unroll
      for (int nt = 0; nt < 4; nt++) {
        acc[mt][nt] = __builtin_amdgcn_mfma_f32_16x16x32_f16(ah[mt], bh[nt], acc[mt][nt], 0, 0, 0);
        acc[mt][nt] = __builtin_amdgcn_mfma_f32_16x16x32_f16(ah[mt], bl[nt], acc[mt][nt], 0, 0, 0);
        acc[mt][nt] = __builtin_amdgcn_mfma_f32_16x16x32_f16(al[mt], bh[nt], acc[mt][nt], 0, 0, 0);
      }
  };

  loadA(0); loadB(0);
  for (int kt = 0; kt < DIN / BK; kt++) {
    convert_write();                 // regs (tile kt) -> LDS
    __syncthreads();                 // LDS ready for all waves
    if (kt + 1 < DIN / BK) { loadA((kt + 1) * BK); loadB((kt + 1) * BK); }  // prefetch under compute
    compute();
    __syncthreads();                 // all waves done reading before overwrite
  }

  // epilogue: C/D layout col=lane&15, row=(lane>>4)*4+reg  [m89-verified]
  const float inv = 1.0f / 8192.0f;  // undo 16*512 scaling
  #pragma unroll
  for (int nt = 0; nt < 4; nt++) {
    int col = col0 + wn + nt * 16 + (lane & 15);
    float bv = bias[col];
    #pragma unroll
    for (int mt = 0; mt < 4; mt++) {
      int rowb = row0 + wm + mt * 16 + ((lane >> 4) << 2);
      #pragma unroll
      for (int r = 0; r < 4; r++)
        C[(size_t)(rowb + r) * NF + col] = acc[mt][nt][r] * inv + bv;
    }
  }
}

// ---------------------------------------------------------------- per-row top-32
// Exact radix-select (4x8-bit passes), ties -> lowest index (matches lax.top_k).
// Row (64 KB) staged into LDS once with coalesced loads; all passes read LDS.
// Global traffic = 1 read + 1 write of the row (structural minimum).
__global__ __launch_bounds__(512, 2) void k_topk(float* __restrict__ pre,
                                                 int* __restrict__ topk_idx,
                                                 float* __restrict__ topk_val,
                                                 int* __restrict__ active) {
  __shared__ __align__(16) float srow[NF];     // 64 KB
  __shared__ unsigned hist[8][256];            // 8 KB, per-wave copies
  __shared__ unsigned redbuf[8];
  __shared__ int sel_idx[KTOP];
  __shared__ float sel_val[KTOP];
  __shared__ unsigned s_prefix;
  __shared__ int s_remaining, s_scnt, s_last;

  const int tid = threadIdx.x;
  const int wv = tid >> 6;                     // 0..7
  const int row = blockIdx.x;
  float* rowp = pre + (size_t)row * NF;

  // stage row into LDS, fully coalesced (lane-stride 16B)
  {
    const float4* g4 = (const float4*)rowp;
    float4* s4 = (float4*)srow;
    #pragma unroll
    for (int i = 0; i < 8; i++) s4[i * 512 + tid] = g4[i * 512 + tid];
  }
  if (tid == 0) { s_prefix = 0u; s_remaining = KTOP; s_scnt = 0; }
  __syncthreads();

  const float4* s4 = (const float4*)srow;

  for (int pass = 0; pass < 4; pass++) {
    const int shift = 24 - pass * 8;
    const unsigned mask_hi = pass ? (0xFFFFFFFFu << (shift + 8)) : 0u;
    {
      unsigned* hp = &hist[0][0];
      #pragma unroll
      for (int q = 0; q < 4; q++) hp[q * 512 + tid] = 0;
    }
    __syncthreads();
    const unsigned pfx = s_prefix;
    #pragma unroll
    for (int i = 0; i < 8; i++) {
      float4 v = s4[i * 512 + tid];
      unsigned k0 = f2k(v.x), k1 = f2k(v.y), k2 = f2k(v.z), k3 = f2k(v.w);
      if ((k0 & mask_hi) == pfx) atomicAdd(&hist[wv][(k0 >> shift) & 255u], 1u);
      if ((k1 & mask_hi) == pfx) atomicAdd(&hist[wv][(k1 >> shift) & 255u], 1u);
      if ((k2 & mask_hi) == pfx) atomicAdd(&hist[wv][(k2 >> shift) & 255u], 1u);
      if ((k3 & mask_hi) == pfx) atomicAdd(&hist[wv][(k3 >> shift) & 255u], 1u);
    }
    __syncthreads();
    if (tid < 256) {
      unsigned h = 0;
      #pragma unroll
      for (int w8 = 0; w8 < 8; w8++) h += hist[w8][tid];
      hist[0][tid] = h;
    }
    __syncthreads();
    if (tid == 0) {
      int rem = s_remaining; unsigned above = 0;
      for (int b = 255; b >= 0; b--) {
        unsigned hh = hist[0][b];
        if (above + hh >= (unsigned)rem) {
          s_prefix |= ((unsigned)b) << shift;
          s_remaining = rem - (int)above;
          break;
        }
        above += hh;
      }
    }
    __syncthreads();
  }
  const unsigned T = s_prefix;   // key of the 32nd largest
  const int r = s_remaining;     // how many ==T to take (lowest indices first)

  // gather strictly-greater (set semantics; order within sel irrelevant)
  #pragma unroll
  for (int i = 0; i < 8; i++) {
    float4 v = s4[i * 512 + tid];
    const int bidx = (i * 512 + tid) * 4;
    float vv[4] = {v.x, v.y, v.z, v.w};
    #pragma unroll
    for (int e = 0; e < 4; e++) {
      unsigned k = f2k(vv[e]);
      if (k > T) {
        int p = atomicAdd(&s_scnt, 1);
        sel_idx[p] = bidx + e;
        sel_val[p] = vv[e];
      }
    }
  }
  __syncthreads();
  // r smallest indices among key==T: iterative block-wide min-index reduction
  const int cg = s_scnt;         // == KTOP - r
  int last = -1;
  const float tv = k2f(T);
  for (int a = 0; a < r; a++) {
    unsigned mymin = 0xFFFFFFFFu;
    #pragma unroll
    for (int i = 0; i < 8; i++) {
      float4 v = s4[i * 512 + tid];
      const int bidx = (i * 512 + tid) * 4;
      float vv[4] = {v.x, v.y, v.z, v.w};
      #pragma unroll
      for (int e = 0; e < 4; e++) {
        int idx = bidx + e;
        if (f2k(vv[e]) == T && idx > last && (unsigned)idx < mymin) mymin = (unsigned)idx;
      }
    }
    #pragma unroll
    for (int o = 32; o > 0; o >>= 1) {
      unsigned ot = __shfl_down(mymin, o);
      mymin = ot < mymin ? ot : mymin;
    }
    if ((tid & 63) == 0) redbuf[wv] = mymin;
    __syncthreads();
    if (tid == 0) {
      unsigned m = redbuf[0];
      #pragma unroll
      for (int w8 = 1; w8 < 8; w8++) m = redbuf[w8] < m ? redbuf[w8] : m;
      sel_idx[cg + a] = (int)m;
      sel_val[cg + a] = tv;
      s_last = (int)m;
    }
    __syncthreads();
    last = s_last;
  }

  // zero the row (coalesced), then scatter relu(top-k)
  float4 z = {0.f, 0.f, 0.f, 0.f};
  float4* wp4 = (float4*)rowp;
  #pragma unroll
  for (int i = 0; i < 8; i++) wp4[i * 512 + tid] = z;
  __syncthreads();
  if (tid < KTOP) {
    int idx = sel_idx[tid];
    float v = sel_val[tid];
    float c = v > 0.f ? v : 0.f;
    rowp[idx] = c;
    topk_idx[row * KTOP + tid] = idx;
    topk_val[row * KTOP + tid] = c;
    if (v > 0.f) active[idx] = 1;
  }
}

// ---------------------------------------------------------------- dead scan (sorted)
__global__ void k_dead(const int* __restrict__ steps, const int* __restrict__ active,
                       int* __restrict__ dead_idx, int* __restrict__ dead_cnt) {
  __shared__ int cnt[256];
  const int tid = threadIdx.x;
  int c = 0;
  for (int f = tid * 64; f < tid * 64 + 64; f++) {
    int ns = active[f] ? 0 : steps[f] + 1;
    if (ns >= DEAD_TH) c++;
  }
  cnt[tid] = c;
  __syncthreads();
  if (tid == 0) {
    int run = 0;
    for (int t = 0; t < 256; t++) { int x = cnt[t]; cnt[t] = run; run += x; }
    *dead_cnt = run;
  }
  __syncthreads();
  int off = cnt[tid];
  for (int f = tid * 64; f < tid * 64 + 64; f++) {
    int ns = active[f] ? 0 : steps[f] + 1;
    if (ns >= DEAD_TH) dead_idx[off++] = f;
  }
}

// ---------------------------------------------------------------- gather dead W_enc columns
__global__ void k_gather(const float* __restrict__ Wenc, const int* __restrict__ dead_idx,
                         const int* __restrict__ dead_cnt, float* __restrict__ w_dead, int Dcap) {
  int D = *dead_cnt; if (D > Dcap) D = Dcap;
  const size_t total = (size_t)D * DIN;
  for (size_t u = (size_t)blockIdx.x * 256 + threadIdx.x; u < total; u += (size_t)gridDim.x * 256) {
    const size_t j = u >> 11, i = u & 2047;
    w_dead[u] = Wenc[i * NF + dead_idx[j]];
  }
}

// ---------------------------------------------------------------- sparse decode + MSE
__global__ __launch_bounds__(256) void k_recon(const float* __restrict__ x, const float* __restrict__ Wdec,
                                               const float* __restrict__ bdec,
                                               const int* __restrict__ topk_idx,
                                               const float* __restrict__ topk_val,
                                               float* __restrict__ recon, double* __restrict__ sums) {
  __shared__ int fidx[KTOP];
  __shared__ float fval[KTOP];
  __shared__ float wred[4];
  const int tid = threadIdx.x, lane = tid & 63, wv = tid >> 6;
  const int row = blockIdx.x;
  if (tid < KTOP) { fidx[tid] = topk_idx[row * KTOP + tid]; fval[tid] = topk_val[row * KTOP + tid]; }
  __syncthreads();
  float4 a0 = {0,0,0,0}, a1 = {0,0,0,0};
  for (int j = 0; j < KTOP; j++) {
    const float c = fval[j];
    if (c > 0.f) {
      const float4* w = (const float4*)(Wdec + (size_t)fidx[j] * DIN);
      float4 w0 = w[tid], w1 = w[256 + tid];
      a0.x = fmaf(c, w0.x, a0.x); a0.y = fmaf(c, w0.y, a0.y);
      a0.z = fmaf(c, w0.z, a0.z); a0.w = fmaf(c, w0.w, a0.w);
      a1.x = fmaf(c, w1.x, a1.x); a1.y = fmaf(c, w1.y, a1.y);
      a1.z = fmaf(c, w1.z, a1.z); a1.w = fmaf(c, w1.w, a1.w);
    }
  }
  const float4* b4 = (const float4*)bdec;
  float4 b0 = b4[tid], b1 = b4[256 + tid];
  float4 r0 = {a0.x + b0.x, a0.y + b0.y, a0.z + b0.z, a0.w + b0.w};
  float4 r1 = {a1.x + b1.x, a1.y + b1.y, a1.z + b1.z, a1.w + b1.w};
  float4* rout = (float4*)(recon + (size_t)row * DIN);
  rout[tid] = r0; rout[256 + tid] = r1;
  const float4* x4 = (const float4*)(x + (size_t)row * DIN);
  float4 x0 = x4[tid], x1 = x4[256 + tid];
  float s = 0.f, d;
  d = r0.x - x0.x; s = fmaf(d, d, s);
  d = r0.y - x0.y; s = fmaf(d, d, s);
  d = r0.z - x0.z; s = fmaf(d, d, s);
  d = r0.w - x0.w; s = fmaf(d, d, s);
  d = r1.x - x1.x; s = fmaf(d, d, s);
  d = r1.y - x1.y; s = fmaf(d, d, s);
  d = r1.z - x1.z; s = fmaf(d, d, s);
  d = r1.w - x1.w; s = fmaf(d, d, s);
  #pragma unroll
  for (int o = 32; o > 0; o >>= 1) s += __shfl_down(s, o);
  if (lane == 0) wred[wv] = s;
  __syncthreads();
  if (tid == 0) {
    double t = (double)wred[0] + (double)wred[1] + (double)wred[2] + (double)wred[3];
    atomicAdd(&sums[0], t);
  }
}

// ---------------------------------------------------------------- aux loss
__global__ __launch_bounds__(256) void k_aux(const float* __restrict__ x, const float* __restrict__ Wenc,
                                             const float* __restrict__ benc, const float* __restrict__ Wdec,
                                             const float* __restrict__ bdec, const float* __restrict__ recon,
                                             const int* __restrict__ dead_idx, const int* __restrict__ dead_cnt,
                                             const float* __restrict__ w_dead, int Dcap,
                                             double* __restrict__ sums) {
  __shared__ float xrow[DIN];
  __shared__ unsigned hist[4][256];
  __shared__ int eqj[2048];
  __shared__ int self_[KAUX];
  __shared__ float selc[KAUX];
  __shared__ float wred[4];
  __shared__ unsigned s_prefix;
  __shared__ int s_remaining, s_scnt, s_eqcnt;

  const int tid = threadIdx.x, lane = tid & 63, wv = tid >> 6;
  const int row = blockIdx.x;
  const float4* xg4 = (const float4*)(x + (size_t)row * DIN);
  float4* xr4 = (float4*)xrow;
  xr4[tid] = xg4[tid];
  xr4[256 + tid] = xg4[256 + tid];
  if (tid == 0) { s_prefix = 0u; s_remaining = KAUX; s_scnt = 0; s_eqcnt = 0; }
  __syncthreads();
  const int D = *dead_cnt;

  auto pdval = [&](int jj) -> float {  // whole wave computes pre of dead feature jj
    const int f = dead_idx[jj];
    float p = 0.f;
    if (jj < Dcap) {
      const float* wd = w_dead + (size_t)jj * DIN;
      for (int i = lane; i < DIN; i += 64) p = fmaf(xrow[i], wd[i], p);
    } else {
      const float* wc = Wenc + f;
      for (int i = lane; i < DIN; i += 64) p = fmaf(xrow[i], wc[(size_t)i * NF], p);
    }
    #pragma unroll
    for (int o = 32; o > 0; o >>= 1) p += __shfl_down(p, o);
    p = __shfl(p, 0);
    return p + benc[f];
  };

  if (D <= KAUX) {
    for (int jj = wv; jj < D; jj += 4) {
      float v = pdval(jj);
      if (lane == 0) { self_[jj] = dead_idx[jj]; selc[jj] = v > 0.f ? v : 0.f; }
    }
    if (tid == 0) s_scnt = D;
    __syncthreads();
  } else {
    for (int pass = 0; pass < 4; pass++) {
      const int shift = 24 - pass * 8;
      const unsigned mask_hi = pass ? (0xFFFFFFFFu << (shift + 8)) : 0u;
      hist[0][tid] = 0; hist[1][tid] = 0; hist[2][tid] = 0; hist[3][tid] = 0;
      __syncthreads();
      const unsigned pfx = s_prefix;
      for (int jj = wv; jj < D; jj += 4) {
        float v = pdval(jj);
        if (lane == 0) {
          unsigned k = f2k(v);
          if ((k & mask_hi) == pfx) atomicAdd(&hist[wv][(k >> shift) & 255u], 1u);
        }
      }
      __syncthreads();
      unsigned h = hist[0][tid] + hist[1][tid] + hist[2][tid] + hist[3][tid];
      hist[0][tid] = h;
      __syncthreads();
      if (tid == 0) {
        int rem = s_remaining; unsigned above = 0;
        for (int b = 255; b >= 0; b--) {
          unsigned hh = hist[0][b];
          if (above + hh >= (unsigned)rem) {
            s_prefix |= ((unsigned)b) << shift;
            s_remaining = rem - (int)above;
            break;
          }
          above += hh;
        }
      }
      __syncthreads();
    }
    const unsigned T = s_prefix;
    const int r = s_remaining;
    for (int jj = wv; jj < D; jj += 4) {
      float v = pdval(jj);
      if (lane == 0) {
        unsigned k = f2k(v);
        if (k > T) { int p = atomicAdd(&s_scnt, 1); self_[p] = dead_idx[jj]; selc[p] = v > 0.f ? v : 0.f; }
        else if (k == T) { int p = atomicAdd(&s_eqcnt, 1); if (p < 2048) eqj[p] = jj; }
      }
    }
    __syncthreads();
    if (tid == 0) {
      int cnt = s_eqcnt < 2048 ? s_eqcnt : 2048;
      const int base = s_scnt;  // == KAUX - r
      const float tv = k2f(T);
      const float tc = tv > 0.f ? tv : 0.f;
      for (int a = 0; a < r; a++) {
        int bestpos = -1, bestj = 0x7fffffff;
        for (int q = 0; q < cnt; q++) { int j = eqj[q]; if (j >= 0 && j < bestj) { bestj = j; bestpos = q; } }
        if (bestpos < 0) break;
        eqj[bestpos] = -1;
        self_[base + a] = dead_idx[bestj];
        selc[base + a] = tc;
      }
      s_scnt = base + r;
    }
    __syncthreads();
  }

  const int scnt = s_scnt;
  float4 a0 = {0,0,0,0}, a1 = {0,0,0,0};
  for (int s = 0; s < scnt; s++) {
    const float c = selc[s];
    if (c > 0.f) {
      const float4* w = (const float4*)(Wdec + (size_t)self_[s] * DIN);
      float4 w0 = w[tid], w1 = w[256 + tid];
      a0.x = fmaf(c, w0.x, a0.x); a0.y = fmaf(c, w0.y, a0.y);
      a0.z = fmaf(c, w0.z, a0.z); a0.w = fmaf(c, w0.w, a0.w);
      a1.x = fmaf(c, w1.x, a1.x); a1.y = fmaf(c, w1.y, a1.y);
      a1.z = fmaf(c, w1.z, a1.z); a1.w = fmaf(c, w1.w, a1.w);
    }
  }
  const float4* b4 = (const float4*)bdec;
  float4 b0 = b4[tid], b1 = b4[256 + tid];
  const float4* rc4 = (const float4*)(recon + (size_t)row * DIN);
  float4 r0 = rc4[tid], r1 = rc4[256 + tid];
  float4 x0 = xr4[tid], x1 = xr4[256 + tid];
  float s = 0.f, d;
  d = (a0.x + b0.x) - (x0.x - r0.x); s = fmaf(d, d, s);
  d = (a0.y + b0.y) - (x0.y - r0.y); s = fmaf(d, d, s);
  d = (a0.z + b0.z) - (x0.z - r0.z); s = fmaf(d, d, s);
  d = (a0.w + b0.w) - (x0.w - r0.w); s = fmaf(d, d, s);
  d = (a1.x + b1.x) - (x1.x - r1.x); s = fmaf(d, d, s);
  d = (a1.y + b1.y) - (x1.y - r1.y); s = fmaf(d, d, s);
  d = (a1.z + b1.z) - (x1.z - r1.z); s = fmaf(d, d, s);
  d = (a1.w + b1.w) - (x1.w - r1.w); s = fmaf(d, d, s);
  #pragma unroll
  for (int o = 32; o > 0; o >>= 1) s += __shfl_down(s, o);
  if (lane == 0) wred[wv] = s;
  __syncthreads();
  if (tid == 0) {
    double t = (double)wred[0] + (double)wred[1] + (double)wred[2] + (double)wred[3];
    atomicAdd(&sums[1], t);
  }
}

// ---------------------------------------------------------------- scalars
__global__ void k_final(const double* __restrict__ sums, float* __restrict__ out_scalars) {
  const double denom = (double)NT * (double)DIN;
  const double mse = sums[0] / denom;
  const double aux = sums[1] / denom;
  out_scalars[0] = (float)(mse + aux);  // loss
  out_scalars[1] = (float)mse;
  out_scalars[2] = (float)aux;
}

// ---------------------------------------------------------------- launch
extern "C" void kernel_launch(void* const* d_in, const int* in_sizes, int n_in,
                              void* d_out, int out_size, void* d_ws, size_t ws_size,
                              hipStream_t stream) {
  const float* x    = (const float*)d_in[0];
  const float* Wenc = (const float*)d_in[1];
  const float* benc = (const float*)d_in[2];
  const float* Wdec = (const float*)d_in[3];
  const float* bdec = (const float*)d_in[4];
  const int*   steps = (const int*)d_in[5];

  float* out = (float*)d_out;
  float* recon   = out;
  float* coeffs  = out + RECON_ELEMS;
  float* scalars = out + RECON_ELEMS + COEFF_ELEMS;

  char* ws = (char*)d_ws;
  size_t off = 0;
  double* sums   = (double*)(ws + off); off += 64;
  int* active    = (int*)(ws + off);    off += (size_t)NF * 4;
  int* dead_cnt  = (int*)(ws + off);    off += 64;
  int* dead_idx  = (int*)(ws + off);    off += (size_t)NF * 4;
  int* topk_idx  = (int*)(ws + off);    off += (size_t)NT * KTOP * 4;
  float* topk_val= (float*)(ws + off);  off += (size_t)NT * KTOP * 4;
  float* w_dead  = (float*)(ws + off);
  int Dcap = 0;
  if (ws_size > off) {
    size_t cap = (ws_size - off) / ((size_t)DIN * 4);
    Dcap = cap > 1024 ? 1024 : (int)cap;
  }

  k_init<<<64, 256, 0, stream>>>(sums, active);
  dim3 gemm_grid(NF / BN, NT / BM);
  k_gemm_mfma<<<gemm_grid, 256, 0, stream>>>(x, Wenc, benc, coeffs);   // pre -> coeffs region
  k_topk<<<NT, 512, 0, stream>>>(coeffs, topk_idx, topk_val, active);  // pre -> sparse coeffs
  k_dead<<<1, 256, 0, stream>>>(steps, active, dead_idx, dead_cnt);
  k_gather<<<256, 256, 0, stream>>>(Wenc, dead_idx, dead_cnt, w_dead, Dcap);
  k_recon<<<NT, 256, 0, stream>>>(x, Wdec, bdec, topk_idx, topk_val, recon, sums);
  k_aux<<<NT, 256, 0, stream>>>(x, Wenc, benc, Wdec, bdec, recon, dead_idx, dead_cnt, w_dead, Dcap, sums);
  k_final<<<1, 1, 0, stream>>>(sums, scalars);
}